// Round 1
// 13034.029 us; speedup vs baseline: 1.3429x; 1.3429x over previous
//
#include <hip/hip_runtime.h>
#include <stdint.h>

#define T_STEPS 2048
#define BATCH 16
#define DIM 1024
#define EPSF 1e-8f

typedef short bf16x8 __attribute__((ext_vector_type(8)));
typedef float f32x4 __attribute__((ext_vector_type(4)));

__device__ __forceinline__ unsigned short f2bf(float f) {
  unsigned u = __float_as_uint(f);
  unsigned r = (u + 0x7fffu + ((u >> 16) & 1u)) >> 16;
  return (unsigned short)r;
}
__device__ __forceinline__ float bf2f(unsigned short b) {
  return __uint_as_float(((unsigned)b) << 16);
}

// ---------------- Threefry-2x32 -> u0 = normalized normal(key(42), 1024) -------------
__global__ void k_threefry_u0(float* __restrict__ u) {
  __shared__ float red[512];
  int tid = threadIdx.x;  // 512 threads
  unsigned k0 = 0u, k1 = 42u;
  unsigned kss[3] = {k0, k1, k0 ^ k1 ^ 0x1BD11BDAu};
  unsigned x0 = (unsigned)tid + k0;
  unsigned x1 = (unsigned)(tid + 512) + k1;
  const int rotsA[4] = {13, 15, 26, 6};
  const int rotsB[4] = {17, 29, 16, 24};
#pragma unroll
  for (int i = 0; i < 5; ++i) {
    const int* r = (i & 1) ? rotsB : rotsA;
#pragma unroll
    for (int j = 0; j < 4; ++j) {
      x0 += x1;
      x1 = (x1 << r[j]) | (x1 >> (32 - r[j]));
      x1 ^= x0;
    }
    x0 += kss[(i + 1) % 3];
    x1 += kss[(i + 2) % 3] + (unsigned)(i + 1);
  }
  const float lo = -0.99999994f;              // nextafter(-1,0) in f32
  const float R = __fsub_rn(1.0f, lo);        // == 2.0f exactly (RNE)
  const float SQRT2 = 1.41421356237309504880f;
  float v0, v1;
  {
    float f = __uint_as_float((x0 >> 9) | 0x3f800000u) - 1.0f;
    float uu = __fadd_rn(__fmul_rn(f, R), lo);
    v0 = SQRT2 * erfinvf(fmaxf(lo, uu));
  }
  {
    float f = __uint_as_float((x1 >> 9) | 0x3f800000u) - 1.0f;
    float uu = __fadd_rn(__fmul_rn(f, R), lo);
    v1 = SQRT2 * erfinvf(fmaxf(lo, uu));
  }
  red[tid] = v0 * v0 + v1 * v1;
  __syncthreads();
  for (int s = 256; s > 0; s >>= 1) {
    if (tid < s) red[tid] += red[tid + s];
    __syncthreads();
  }
  float nrm = sqrtf(red[0]);
  u[tid] = v0 / nrm;
  u[tid + 512] = v1 / nrm;
}

// ---------------- power iteration pieces ----------------
__global__ void k_wt_u(const float* __restrict__ W, const float* __restrict__ u,
                       float* __restrict__ vraw) {
  __shared__ float red[4][64];
  int tid = threadIdx.x;
  int cl = tid & 63, rp = tid >> 6;
  int c = blockIdx.x * 64 + cl;
  float acc = 0.f;
  for (int r = rp; r < 1024; r += 4) acc += W[(size_t)r * 1024 + c] * u[r];
  red[rp][cl] = acc;
  __syncthreads();
  if (rp == 0) vraw[c] = red[0][cl] + red[1][cl] + red[2][cl] + red[3][cl];
}

__global__ void k_w_v(const float* __restrict__ W, const float* __restrict__ v,
                      float* __restrict__ uraw) {
  __shared__ float red[64][4];
  int tid = threadIdx.x;
  int rl = tid >> 2, cp = tid & 3;
  int r = blockIdx.x * 64 + rl;
  const float* Wr = W + (size_t)r * 1024 + cp * 256;
  const float* vp = v + cp * 256;
  float acc = 0.f;
  for (int i = 0; i < 256; i += 4) {
    float4 wv = *(const float4*)(Wr + i);
    float4 vv = *(const float4*)(vp + i);
    acc += wv.x * vv.x + wv.y * vv.y + wv.z * vv.z + wv.w * vv.w;
  }
  red[rl][cp] = acc;
  __syncthreads();
  if (cp == 0) uraw[r] = red[rl][0] + red[rl][1] + red[rl][2] + red[rl][3];
}

__global__ void k_normalize(const float* __restrict__ raw, float* __restrict__ out, float eps) {
  __shared__ float red[256];
  int tid = threadIdx.x;
  float s = 0.f;
  for (int i = tid; i < 1024; i += 256) { float xv = raw[i]; s += xv * xv; }
  red[tid] = s;
  __syncthreads();
  for (int k = 128; k > 0; k >>= 1) {
    if (tid < k) red[tid] += red[tid + k];
    __syncthreads();
  }
  float d = sqrtf(red[0]) + eps;
  for (int i = tid; i < 1024; i += 256) out[i] = raw[i] / d;
}

__global__ void k_sigma(const float* __restrict__ u, const float* __restrict__ uraw,
                        float* __restrict__ scale) {
  __shared__ float red[256];
  int tid = threadIdx.x;
  float s = 0.f;
  for (int i = tid; i < 1024; i += 256) s += u[i] * uraw[i];
  red[tid] = s;
  __syncthreads();
  for (int k = 128; k > 0; k >>= 1) {
    if (tid < k) red[tid] += red[tid + k];
    __syncthreads();
  }
  if (tid == 0) scale[0] = 0.99f / (fabsf(red[0]) + EPSF);
}

// ---------------- split fp32 -> bf16 hi/lo (optional scale) ----------------
__global__ void k_split(const float* __restrict__ src, unsigned short* __restrict__ hi,
                        unsigned short* __restrict__ lo, const float* __restrict__ scale_ptr,
                        int use_scale, int n4) {
  int idx = blockIdx.x * blockDim.x + threadIdx.x;
  if (idx >= n4) return;
  float s = use_scale ? scale_ptr[0] : 1.0f;
  float4 v = *(const float4*)(src + (size_t)idx * 4);
  float w[4] = {v.x * s, v.y * s, v.z * s, v.w * s};
  unsigned short ho[4], lvo[4];
#pragma unroll
  for (int j = 0; j < 4; ++j) {
    ho[j] = f2bf(w[j]);
    lvo[j] = f2bf(w[j] - bf2f(ho[j]));
  }
  *(ushort4*)(hi + (size_t)idx * 4) = make_ushort4(ho[0], ho[1], ho[2], ho[3]);
  *(ushort4*)(lo + (size_t)idx * 4) = make_ushort4(lvo[0], lvo[1], lvo[2], lvo[3]);
}

// ---------------- a_scale = x@W_a ; rw = softmax(x@W_w) ----------------
__global__ void k_ascale_rw(const float* __restrict__ x, const float* __restrict__ W_a,
                            const float* __restrict__ W_w, float* __restrict__ ascale,
                            float* __restrict__ rwout) {
  __shared__ float ra[16][16][4];
  __shared__ float rb[16][16][4];
  int t = blockIdx.x, tid = threadIdx.x;
  int b = tid >> 4, cp = tid & 15;
  const float* xr = x + ((size_t)(t * 16 + b)) * 1024 + cp * 64;
  float aa[4] = {0, 0, 0, 0}, ww[4] = {0, 0, 0, 0};
  for (int i = 0; i < 64; i += 4) {
    float4 xv = *(const float4*)(xr + i);
    float xs[4] = {xv.x, xv.y, xv.z, xv.w};
    int c = cp * 64 + i;
#pragma unroll
    for (int j = 0; j < 4; ++j) {
      float4 wa = *(const float4*)(W_a + (size_t)(c + j) * 4);
      float4 wb = *(const float4*)(W_w + (size_t)(c + j) * 4);
      aa[0] += xs[j] * wa.x; aa[1] += xs[j] * wa.y; aa[2] += xs[j] * wa.z; aa[3] += xs[j] * wa.w;
      ww[0] += xs[j] * wb.x; ww[1] += xs[j] * wb.y; ww[2] += xs[j] * wb.z; ww[3] += xs[j] * wb.w;
    }
  }
#pragma unroll
  for (int k = 0; k < 4; ++k) { ra[b][cp][k] = aa[k]; rb[b][cp][k] = ww[k]; }
  __syncthreads();
  if (tid < 16) {
    int bb = tid;
    float sa[4] = {0, 0, 0, 0}, sw[4] = {0, 0, 0, 0};
    for (int c2 = 0; c2 < 16; ++c2)
#pragma unroll
      for (int k = 0; k < 4; ++k) { sa[k] += ra[bb][c2][k]; sw[k] += rb[bb][c2][k]; }
    float mx = fmaxf(fmaxf(sw[0], sw[1]), fmaxf(sw[2], sw[3]));
    float e[4], es = 0.f;
#pragma unroll
    for (int k = 0; k < 4; ++k) { e[k] = expf(sw[k] - mx); es += e[k]; }
#pragma unroll
    for (int k = 0; k < 4; ++k) {
      ascale[((size_t)(t * 16 + bb)) * 4 + k] = sa[k];
      rwout[((size_t)(t * 16 + bb)) * 4 + k] = e[k] / es;
    }
  }
}

// ---------------- precompute xwx = x @ W_x^T + b (f32 out) ----------------
// grid 2048: cblk = bid&63 (16 output cols), tc = bid>>6 (64 timesteps).
// Consecutive bids share tc -> co-resident blocks share the x chunk in L2/L3.
__global__ __launch_bounds__(256) void k_xwx(const float* __restrict__ x,
                                             const unsigned short* __restrict__ Wxhi,
                                             const unsigned short* __restrict__ Wxlo,
                                             const float* __restrict__ bias,
                                             float* __restrict__ xwx) {
  const int tid = threadIdx.x;
  const int cblk = blockIdx.x & 63;
  const int tc = blockIdx.x >> 6;
  const int wv = tid >> 6;
  const int lane = tid & 63;
  const int fn = lane & 15;
  const int kg = lane >> 4;

  __shared__ float red[4][4][64];  // [kgroup][reg][lane] - conflict-free

  bf16x8 bWx_hi[8], bWx_lo[8];
  {
    int r = cblk * 16 + fn;
#pragma unroll
    for (int c = 0; c < 8; ++c) {
      int k = wv * 256 + c * 32 + kg * 8;
      bWx_hi[c] = *(const bf16x8*)(Wxhi + (size_t)r * 1024 + k);
      bWx_lo[c] = *(const bf16x8*)(Wxlo + (size_t)r * 1024 + k);
    }
  }
  const int bb = kg * 4 + wv;        // this wave's output batch row set
  const int col = cblk * 16 + fn;    // output dim
  const float bias_r = bias[col];

  for (int sl = 0; sl < 64; ++sl) {
    const int s = tc * 64 + sl;
    f32x4 acc0 = {0.f, 0.f, 0.f, 0.f}, acc1 = {0.f, 0.f, 0.f, 0.f};
#pragma unroll
    for (int c = 0; c < 8; ++c) {
      int k = wv * 256 + c * 32 + kg * 8;
      const float* xp = x + ((size_t)(s * 16 + fn)) * 1024 + k;
      float4 q0 = *(const float4*)(xp);
      float4 q1 = *(const float4*)(xp + 4);
      float xs[8] = {q0.x, q0.y, q0.z, q0.w, q1.x, q1.y, q1.z, q1.w};
      bf16x8 axh, axl;
#pragma unroll
      for (int j = 0; j < 8; ++j) {
        unsigned short h_ = f2bf(xs[j]);
        axh[j] = (short)h_;
        axl[j] = (short)f2bf(xs[j] - bf2f(h_));
      }
      if ((c & 1) == 0) {
        acc0 = __builtin_amdgcn_mfma_f32_16x16x32_bf16(axh, bWx_hi[c], acc0, 0, 0, 0);
        acc0 = __builtin_amdgcn_mfma_f32_16x16x32_bf16(axl, bWx_hi[c], acc0, 0, 0, 0);
        acc0 = __builtin_amdgcn_mfma_f32_16x16x32_bf16(axh, bWx_lo[c], acc0, 0, 0, 0);
      } else {
        acc1 = __builtin_amdgcn_mfma_f32_16x16x32_bf16(axh, bWx_hi[c], acc1, 0, 0, 0);
        acc1 = __builtin_amdgcn_mfma_f32_16x16x32_bf16(axl, bWx_hi[c], acc1, 0, 0, 0);
        acc1 = __builtin_amdgcn_mfma_f32_16x16x32_bf16(axh, bWx_lo[c], acc1, 0, 0, 0);
      }
    }
#pragma unroll
    for (int r = 0; r < 4; ++r) red[wv][r][lane] = acc0[r] + acc1[r];
    __syncthreads();
    {
      float ssum = red[0][wv][lane] + red[1][wv][lane] + red[2][wv][lane] +
                   red[3][wv][lane] + bias_r;
      xwx[((size_t)(s * 16 + bb)) * 1024 + col] = ssum;
    }
    __syncthreads();
  }
}

#define FLAG_STRIDE 32  // dwords: one flag per 128B line (spread across LLC slices)

// ---------------- persistent scan kernel: 64 blocks x 256 threads ----------------
__global__ __launch_bounds__(256, 1) void k_persistent(
    const float* __restrict__ xwx, const float* __restrict__ z, const float* __restrict__ h0,
    const float* __restrict__ m0, const float* __restrict__ a,
    const unsigned short* __restrict__ Whhi, const unsigned short* __restrict__ Whlo,
    const float* __restrict__ ascale, const float* __restrict__ rw, unsigned* __restrict__ hpk,
    unsigned* __restrict__ flags, float* __restrict__ out, float* __restrict__ hf,
    float* __restrict__ mf) {
  const int tid = threadIdx.x;
  const int blk = blockIdx.x;  // 0..63, owns dims [blk*16, blk*16+16)
  const int wv = tid >> 6;     // 0..3, owns K slice [wv*256, wv*256+256)
  const int lane = tid & 63;
  const int fn = lane & 15;  // MFMA n/m index
  const int kg = lane >> 4;  // MFMA k-group

  __shared__ float red[4][4][64];   // [kgroup][reg][lane] - conflict-free layout
  __shared__ float hn_lds[16][17];  // [b][d_local], padded vs bank conflicts

  // permanent B fragments (W_h rows in registers)
  bf16x8 bWh_hi[8], bWh_lo[8];
  {
    int r = blk * 16 + fn;
#pragma unroll
    for (int c = 0; c < 8; ++c) {
      int k = wv * 256 + c * 32 + kg * 8;
      bWh_hi[c] = *(const bf16x8*)(Whhi + (size_t)r * 1024 + k);
      bWh_lo[c] = *(const bf16x8*)(Whlo + (size_t)r * 1024 + k);
    }
  }

  // phase-3 (elementwise) identity
  const int p_b = tid >> 4;
  const int p_dl = tid & 15;
  const int p_d = blk * 16 + p_dl;
  float m_reg[4], a_reg[4];
#pragma unroll
  for (int k2 = 0; k2 < 4; ++k2) {
    m_reg[k2] = m0[((size_t)(k2 * 16 + p_b)) * 1024 + p_d];
    a_reg[k2] = a[(size_t)k2 * 1024 + p_d];
  }

  // distributed-tail identity: each wave owns reg=wv -> rows {wv,4+wv,8+wv,12+wv}
  const int bb = kg * 4 + wv;
  const int col = blk * 16 + fn;

  // production 0: h0 -> packed hi/lo in buffer 0
  {
    float v = h0[(size_t)p_b * 1024 + p_d];
    unsigned short h_ = f2bf(v);
    unsigned short l_ = f2bf(v - bf2f(h_));
    unsigned pk = ((unsigned)h_ << 16) | (unsigned)l_;
    __hip_atomic_store(hpk + ((size_t)p_b * 1024 + p_d), pk, __ATOMIC_RELAXED,
                       __HIP_MEMORY_SCOPE_AGENT);
  }
  asm volatile("s_waitcnt vmcnt(0)" ::: "memory");
  __syncthreads();
  if (tid == 0)
    __hip_atomic_store(flags + (size_t)blk * FLAG_STRIDE, 1u, __ATOMIC_RELAXED,
                       __HIP_MEMORY_SCOPE_AGENT);

  const unsigned* prodFlag = flags + (size_t)(16 * wv + fn) * FLAG_STRIDE;

  for (int s = 0; s < T_STEPS; ++s) {
    const unsigned* hsrc = hpk + (size_t)(s & 1) * 16384;
    unsigned* hdst = hpk + (size_t)((s + 1) & 1) * 16384;

    // ---- prefetch this step's precomputed x-projection + phase-3 operands
    const float xwf = xwx[((size_t)(s * 16 + bb)) * 1024 + col];
    const float4 asc = *(const float4*)(ascale + ((size_t)(s * 16 + p_b)) * 4);
    const float4 rwv4 = *(const float4*)(rw + ((size_t)(s * 16 + p_b)) * 4);
    const float zh = z[((size_t)(s * 16 + p_b)) * 2048 + p_d];
    const float zm = z[((size_t)(s * 16 + p_b)) * 2048 + 1024 + p_d];
    asm volatile("" ::: "memory");

    // ---- wait for this wave's 16 producers (padded flags: 1 per 128B line)
    {
      unsigned target = (unsigned)(s + 1);
      int iter = 0;
      while (true) {
        unsigned f = __hip_atomic_load(prodFlag, __ATOMIC_RELAXED, __HIP_MEMORY_SCOPE_AGENT);
        if (__all((int)(f >= target))) break;
        if (++iter > (1 << 22)) break;  // escape hatch (never expected)
        __builtin_amdgcn_s_sleep(1);
      }
    }
    asm volatile("" ::: "memory");

    // ---- load h fragments (packed hi|lo), agent-scope so they come from coherence point
    unsigned hw[8][8];
#pragma unroll
    for (int c = 0; c < 8; ++c) {
      int k = wv * 256 + c * 32 + kg * 8;
      const unsigned* hp = hsrc + (size_t)fn * 1024 + k;
#pragma unroll
      for (int q = 0; q < 4; ++q) {
        unsigned long long d2 = __hip_atomic_load((const unsigned long long*)(hp + q * 2),
                                                  __ATOMIC_RELAXED, __HIP_MEMORY_SCOPE_AGENT);
        hw[c][q * 2] = (unsigned)d2;
        hw[c][q * 2 + 1] = (unsigned)(d2 >> 32);
      }
    }

    // ---- MFMA: h part only (x part precomputed). hi/lo 3-product, 2 dep chains.
    f32x4 acc0 = {0.f, 0.f, 0.f, 0.f}, acc1 = {0.f, 0.f, 0.f, 0.f};
#pragma unroll
    for (int c = 0; c < 8; ++c) {
      bf16x8 ahh, ahl;
#pragma unroll
      for (int j = 0; j < 8; ++j) {
        unsigned pk = hw[c][j];
        ahh[j] = (short)(pk >> 16);
        ahl[j] = (short)(pk & 0xffffu);
      }
      if ((c & 1) == 0) {
        acc0 = __builtin_amdgcn_mfma_f32_16x16x32_bf16(ahh, bWh_hi[c], acc0, 0, 0, 0);
        acc0 = __builtin_amdgcn_mfma_f32_16x16x32_bf16(ahl, bWh_hi[c], acc0, 0, 0, 0);
        acc0 = __builtin_amdgcn_mfma_f32_16x16x32_bf16(ahh, bWh_lo[c], acc0, 0, 0, 0);
      } else {
        acc1 = __builtin_amdgcn_mfma_f32_16x16x32_bf16(ahh, bWh_hi[c], acc1, 0, 0, 0);
        acc1 = __builtin_amdgcn_mfma_f32_16x16x32_bf16(ahl, bWh_hi[c], acc1, 0, 0, 0);
        acc1 = __builtin_amdgcn_mfma_f32_16x16x32_bf16(ahh, bWh_lo[c], acc1, 0, 0, 0);
      }
    }

    // ---- cross-wave K reduction, tail distributed over all 4 waves (reg = wv)
#pragma unroll
    for (int r = 0; r < 4; ++r) red[wv][r][lane] = acc0[r] + acc1[r];
    __syncthreads();
    {
      float ssum = red[0][wv][lane] + red[1][wv][lane] + red[2][wv][lane] +
                   red[3][wv][lane] + xwf;
      float hv = tanhf(ssum);
      hn_lds[bb][fn] = hv;
      unsigned short h_ = f2bf(hv);
      unsigned short l_ = f2bf(hv - bf2f(h_));
      unsigned pk = ((unsigned)h_ << 16) | (unsigned)l_;
      __hip_atomic_store(hdst + (size_t)bb * 1024 + col, pk, __ATOMIC_RELAXED,
                         __HIP_MEMORY_SCOPE_AGENT);
    }
    asm volatile("s_waitcnt vmcnt(0)" ::: "memory");
    __syncthreads();
    if (tid == 0)
      __hip_atomic_store(flags + (size_t)blk * FLAG_STRIDE, (unsigned)(s + 2), __ATOMIC_RELAXED,
                         __HIP_MEMORY_SCOPE_AGENT);

    // ---- phase 3 (local): m update + output, overlaps other blocks' latency
    {
      float hv = hn_lds[p_b][p_dl];
      float ascv[4] = {asc.x, asc.y, asc.z, asc.w};
      float rwc[4] = {rwv4.x, rwv4.y, rwv4.z, rwv4.w};
      float mo = 0.f;
#pragma unroll
      for (int k2 = 0; k2 < 4; ++k2) {
        float al = 1.f / (1.f + expf(-(a_reg[k2] + ascv[k2])));
        float mm = al * m_reg[k2] + (1.f - al) * hv;
        m_reg[k2] = mm;
        mo += rwc[k2] * mm;
      }
      float sh = zh / (1.f + expf(-zh));
      float sm = zm / (1.f + expf(-zm));
      out[((size_t)(s * 16 + p_b)) * 1024 + p_d] = hv * sh + mo * sm;
    }
  }

  // final states
  hf[(size_t)p_b * 1024 + p_d] = hn_lds[p_b][p_dl];
#pragma unroll
  for (int k2 = 0; k2 < 4; ++k2)
    mf[((size_t)(k2 * 16 + p_b)) * 1024 + p_d] = m_reg[k2];
}

extern "C" void kernel_launch(void* const* d_in, const int* in_sizes, int n_in, void* d_out,
                              int out_size, void* d_ws, size_t ws_size, hipStream_t stream) {
  const float* x = (const float*)d_in[0];
  const float* z = (const float*)d_in[1];
  const float* h0 = (const float*)d_in[2];
  const float* m0 = (const float*)d_in[3];
  const float* W_x = (const float*)d_in[4];
  const float* W_h = (const float*)d_in[5];
  const float* bias = (const float*)d_in[6];
  const float* a = (const float*)d_in[7];
  const float* W_a = (const float*)d_in[8];
  const float* W_w = (const float*)d_in[9];
  float* out = (float*)d_out;
  float* hf = out + (size_t)T_STEPS * BATCH * DIM;
  float* mf = hf + (size_t)BATCH * DIM;

  char* ws = (char*)d_ws;
  size_t off = 0;
  auto alloc = [&](size_t bytes) -> void* {
    void* p = (void*)(ws + off);
    off += (bytes + 255) & ~(size_t)255;
    return p;
  };
  float* scale = (float*)alloc(256);
  float* u_ = (float*)alloc(4096);
  float* v_ = (float*)alloc(4096);
  float* t1 = (float*)alloc(4096);
  unsigned* flags = (unsigned*)alloc(64 * FLAG_STRIDE * 4);
  unsigned* hpk = (unsigned*)alloc(2 * 16384 * 4);
  unsigned short* Whhi = (unsigned short*)alloc((size_t)1024 * 1024 * 2);
  unsigned short* Whlo = (unsigned short*)alloc((size_t)1024 * 1024 * 2);
  unsigned short* Wxhi = (unsigned short*)alloc((size_t)1024 * 1024 * 2);
  unsigned short* Wxlo = (unsigned short*)alloc((size_t)1024 * 1024 * 2);
  float* ascale = (float*)alloc((size_t)T_STEPS * 16 * 4 * 4);
  float* rwbuf = (float*)alloc((size_t)T_STEPS * 16 * 4 * 4);
  float* xwx = (float*)alloc((size_t)T_STEPS * BATCH * DIM * 4);  // 128 MB

  hipMemsetAsync(flags, 0, 64 * FLAG_STRIDE * 4, stream);
  k_threefry_u0<<<1, 512, 0, stream>>>(u_);
  for (int i = 0; i < 3; ++i) {
    k_wt_u<<<16, 256, 0, stream>>>(W_h, u_, t1);
    k_normalize<<<1, 256, 0, stream>>>(t1, v_, EPSF);
    k_w_v<<<16, 256, 0, stream>>>(W_h, v_, t1);
    k_normalize<<<1, 256, 0, stream>>>(t1, u_, EPSF);
  }
  k_sigma<<<1, 256, 0, stream>>>(u_, t1, scale);
  k_split<<<1024, 256, 0, stream>>>(W_h, Whhi, Whlo, scale, 1, 262144);
  k_split<<<1024, 256, 0, stream>>>(W_x, Wxhi, Wxlo, scale, 0, 262144);
  k_ascale_rw<<<T_STEPS, 256, 0, stream>>>(x, W_a, W_w, ascale, rwbuf);
  k_xwx<<<2048, 256, 0, stream>>>(x, Wxhi, Wxlo, bias, xwx);
  k_persistent<<<64, 256, 0, stream>>>(xwx, z, h0, m0, a, Whhi, Whlo, ascale, rwbuf, hpk,
                                       flags, out, hf, mf);
}